// Round 10
// baseline (126.395 us; speedup 1.0000x reference)
//
#include <hip/hip_runtime.h>
#include <hip/hip_fp16.h>
#include <stdint.h>

#define LN_EPS 1e-5f
#define G1 256
#define P1CAP 4096
#define P3CAP 6144
#define CAPB 6144

typedef __attribute__((ext_vector_type(8))) short s16x8;
typedef __attribute__((ext_vector_type(4))) float f32x4;

__device__ __forceinline__ float b2f(unsigned short u) {
    union { unsigned int i; float f; } v; v.i = ((unsigned int)u) << 16; return v.f;
}
__device__ __forceinline__ unsigned short f2b(float f) {
    union { float f; unsigned int i; } v; v.f = f;
    unsigned int u = v.i;
    return (unsigned short)((u + 0x7fffu + ((u >> 16) & 1u)) >> 16);
}
__device__ __forceinline__ unsigned int pk2(float a, float b) {
    return (unsigned int)f2b(a) | ((unsigned int)f2b(b) << 16);
}
__device__ __forceinline__ __half2 u2h2(unsigned int u) {
    union { unsigned int i; __half2 h; } v; v.i = u; return v.h;
}

__device__ __forceinline__ float rdf(const void* p, int i, int f32flag) {
    return f32flag ? ((const float*)p)[i] : b2f(((const unsigned short*)p)[i]);
}

// pass 1 (320 blocks): blocks [0,256) bin edges by bucket (dst>>8);
// blocks [256,320) transpose W1/W2 -> bf16 and convert small params.
// Every block locally re-derives dtype flags; block 0 publishes them.
__global__ __launch_bounds__(256) void k_p1(const unsigned short* __restrict__ xu,
                                            const int* __restrict__ ei, const void* __restrict__ ew,
                                            const void* W1, const void* W2,
                                            const void* b1, const void* b2_,
                                            const void* g1, const void* g2,
                                            const void* be1, const void* be2,
                                            unsigned short* __restrict__ Wt1,
                                            unsigned short* __restrict__ Wt2,
                                            float* __restrict__ sm,
                                            int E, int B, int chunk,
                                            unsigned int* __restrict__ gA,
                                            unsigned char* __restrict__ g8,
                                            int* __restrict__ cnt2d, int* __restrict__ lofs2d,
                                            int* __restrict__ flags) {
    __shared__ int hist[256], cur[256], tmp[256];
    __shared__ unsigned int bin32[P1CAP];
    __shared__ unsigned char bin8[P1CAP];
    int t = threadIdx.x, g = blockIdx.x;
    // ---- local dtype detection ----
    if (t < 2) hist[t] = 0;
    __syncthreads();
    int c1 = 0;
    for (int i = t; i < 2048; i += 256)
        if (fabsf(b2f(xu[i])) > 1e6f) ++c1;
    if (c1) atomicAdd(&hist[0], c1);
    int mn = (E < 1024) ? E : 1024;
    int z = 0;
    for (int i = t; i < mn; i += 256)
        if (ei[2 * i + 1] == 0) ++z;
    if (z) atomicAdd(&hist[1], z);
    __syncthreads();
    int f32f = (hist[0] > 32) ? 1 : 0;
    int f64  = (hist[1] > (mn >> 1)) ? 1 : 0;
    if (g == 0 && t == 0) { flags[0] = f32f; flags[1] = f64; }

    if (g >= G1) {
        // ---- prep role ----
        int i = (g - G1) * 256 + t;      // 64*256 = 16384
        int k = i >> 7, j = i & 127;
        Wt1[j * 128 + k] = f2b(rdf(W1, i, f32f));
        Wt2[j * 128 + k] = f2b(rdf(W2, i, f32f));
        if (g == G1 && t < 128) {
            sm[t]       = rdf(b1, t, f32f);
            sm[128 + t] = rdf(b2_, t, f32f);
            sm[256 + t] = rdf(g1, t, f32f);
            sm[384 + t] = rdf(g2, t, f32f);
            sm[512 + t] = rdf(be1, t, f32f);
            sm[640 + t] = rdf(be2, t, f32f);
        }
        return;
    }
    __syncthreads();
    // ---- binning ----
    int base = g * chunk;
    int cnt = E - base; if (cnt > chunk) cnt = chunk; if (cnt < 0) cnt = 0;
    hist[t] = 0;
    __syncthreads();
    for (int i = t; i < cnt; i += 256) {
        int e = base + i;
        int d = f64 ? ei[2 * E + 2 * e] : ei[E + e];
        atomicAdd(&hist[d >> 8], 1);
    }
    __syncthreads();
    int v = hist[t];
    tmp[t] = v;
    __syncthreads();
    for (int d = 1; d < 256; d <<= 1) {
        int x = (t >= d) ? tmp[t - d] : 0;
        __syncthreads();
        tmp[t] += x;
        __syncthreads();
    }
    int excl = tmp[t] - v;
    cur[t] = excl;
    if (t < B) { cnt2d[t * G1 + g] = v; lofs2d[t * G1 + g] = excl; }
    __syncthreads();
    for (int i = t; i < cnt; i += 256) {
        int e = base + i;
        int d, sN;
        if (f64) { d = ei[2 * E + 2 * e]; sN = ei[2 * e]; }
        else     { d = ei[E + e];         sN = ei[e]; }
        float w = f32f ? ((const float*)ew)[e] : b2f(((const unsigned short*)ew)[e]);
        __half wh = __float2half(w);
        int p = atomicAdd(&cur[d >> 8], 1);
        bin32[p] = (unsigned int)(sN & 0xffff) | ((unsigned int)__half_as_ushort(wh) << 16);
        bin8[p]  = (unsigned char)(d & 255);
    }
    __syncthreads();
    for (int j = t; j < cnt; j += 256) {
        gA[base + j] = bin32[j];
        g8[base + j] = bin8[j];
    }
}

// pass 3: gather bucket's block-segments into LDS, sort by exact dst,
// write 8-aligned zero-padded segments; nfo stored in DEGREE-RANK order
// (nfo[node0+rank] = {start, deg | localid<<16}) for wave load balance.
__global__ __launch_bounds__(256) void k_p3(const unsigned int* __restrict__ gA,
                                            const unsigned char* __restrict__ g8,
                                            const int* __restrict__ cnt2d,
                                            const int* __restrict__ lofs2d,
                                            unsigned int* __restrict__ edata,
                                            uint2* __restrict__ nfo,
                                            int N, int B, int chunk) {
    __shared__ unsigned int raw[P3CAP];
    __shared__ unsigned int srt[CAPB];
    __shared__ unsigned char r8[P3CAP];
    __shared__ int h[256], tmp[256];
    __shared__ int s_cnt;
    int b = blockIdx.x, t = threadIdx.x;
    int segc = cnt2d[b * G1 + t];
    int sbase = t * chunk + lofs2d[b * G1 + t];
    // scan segment lengths -> LDS gather offsets
    int v = segc;
    tmp[t] = v;
    __syncthreads();
    for (int d = 1; d < 256; d <<= 1) {
        int x = (t >= d) ? tmp[t - d] : 0;
        __syncthreads();
        tmp[t] += x;
        __syncthreads();
    }
    int lo = tmp[t] - v;
    if (t == 255) s_cnt = tmp[255];
    // gather my segment into LDS, 4 independent loads in flight
    int j = 0;
    for (; j + 3 < segc; j += 4) {
        unsigned int a0 = gA[sbase + j], a1 = gA[sbase + j + 1];
        unsigned int a2 = gA[sbase + j + 2], a3 = gA[sbase + j + 3];
        unsigned char c0 = g8[sbase + j], c1 = g8[sbase + j + 1];
        unsigned char c2 = g8[sbase + j + 2], c3 = g8[sbase + j + 3];
        int i0 = lo + j;
        if (i0 + 3 < P3CAP) {
            raw[i0] = a0; raw[i0 + 1] = a1; raw[i0 + 2] = a2; raw[i0 + 3] = a3;
            r8[i0] = c0; r8[i0 + 1] = c1; r8[i0 + 2] = c2; r8[i0 + 3] = c3;
        }
    }
    for (; j < segc; ++j) {
        int idx = lo + j;
        if (idx < P3CAP) { raw[idx] = gA[sbase + j]; r8[idx] = g8[sbase + j]; }
    }
    h[t] = 0;
    __syncthreads();
    int cnt = s_cnt; if (cnt > P3CAP) cnt = P3CAP;
    for (int i = t; i < cnt; i += 256) atomicAdd(&h[r8[i]], 1);
    __syncthreads();
    int deg = h[t];
    int pd = (deg + 7) & ~7;
    tmp[t] = pd;
    __syncthreads();
    for (int d = 1; d < 256; d <<= 1) {
        int x = (t >= d) ? tmp[t - d] : 0;
        __syncthreads();
        tmp[t] += x;
        __syncthreads();
    }
    int pexcl = tmp[t] - pd;
    int padTot = tmp[255]; if (padTot > CAPB) padTot = CAPB;
    int node0 = b << 8;
    int nn = N - node0; if (nn > 256) nn = 256;
    int gbase = b * CAPB;
    h[t] = pexcl;
    for (int i = t; i < padTot; i += 256) srt[i] = 0;
    __syncthreads();
    for (int i = t; i < cnt; i += 256) {
        int p = atomicAdd(&h[r8[i]], 1);
        if (p < CAPB) srt[p] = raw[i];
    }
    __syncthreads();
    for (int i = t; i < padTot; i += 256) edata[gbase + i] = srt[i];
    // ---- degree-rank the bucket's nodes for balanced agg waves ----
    h[t] = 0;
    __syncthreads();
    int dcl = (deg > 255) ? 255 : deg;
    if (t < nn) atomicAdd(&h[dcl], 1);
    __syncthreads();
    v = h[t];
    tmp[t] = v;
    __syncthreads();
    for (int d = 1; d < 256; d <<= 1) {
        int x = (t >= d) ? tmp[t - d] : 0;
        __syncthreads();
        tmp[t] += x;
        __syncthreads();
    }
    int excl2 = tmp[t] - v;
    __syncthreads();
    h[t] = excl2;
    __syncthreads();
    if (t < nn) {
        int rank = atomicAdd(&h[dcl], 1);
        nfo[node0 + rank] = make_uint2((unsigned)(gbase + pexcl),
                                       (unsigned)deg | ((unsigned)t << 16));
    }
}

// MFMA bf16 GEMM: H[n][j] = sum_k X[n][k]*W[k][j]; output stored as f16.
__global__ __launch_bounds__(256) void k_gemm(const void* __restrict__ X,
                                              const unsigned short* __restrict__ Wt,
                                              unsigned short* __restrict__ Hh, int N,
                                              const int* __restrict__ flags, int layer1) {
    __shared__ unsigned char lds[49152];   // xs 16KB + wt 32KB
    unsigned char* xs = lds;
    unsigned char* wt = lds + 16384;
    int t = threadIdx.x;
    int node0 = blockIdx.x * 64;
    int f32in = layer1 ? flags[0] : 0;

#pragma unroll
    for (int it = 0; it < 8; ++it) {
        int c = t + it * 256;
        int row = c >> 4, cc = c & 15;
        uint4 v = *(const uint4*)(Wt + row * 128 + cc * 8);
        int off = (row * 256 + cc * 16) ^ ((row & 7) << 4);
        *(uint4*)(wt + off) = v;
    }
#pragma unroll
    for (int it = 0; it < 4; ++it) {
        int c = t + it * 256;
        int row = c >> 4, cc = c & 15;
        int g = node0 + row;
        uint4 v = make_uint4(0, 0, 0, 0);
        if (g < N) {
            if (f32in) {
                const float* xr = (const float*)X + (size_t)g * 128 + cc * 8;
                float4 f0 = *(const float4*)xr;
                float4 f1 = *(const float4*)(xr + 4);
                v.x = pk2(f0.x, f0.y); v.y = pk2(f0.z, f0.w);
                v.z = pk2(f1.x, f1.y); v.w = pk2(f1.z, f1.w);
            } else {
                v = *(const uint4*)((const unsigned short*)X + (size_t)g * 128 + cc * 8);
            }
        }
        int off = (row * 256 + cc * 16) ^ ((row & 7) << 4);
        *(uint4*)(xs + off) = v;
    }
    __syncthreads();

    int w = t >> 6, l = t & 63;
    int arow = l & 15;
    int apart = l >> 4;
    f32x4 acc[8];
#pragma unroll
    for (int ct = 0; ct < 8; ++ct) acc[ct] = (f32x4){0.f, 0.f, 0.f, 0.f};

#pragma unroll
    for (int ks = 0; ks < 4; ++ks) {
        int grow = w * 16 + arow;
        int aoff = (grow * 256 + ks * 64 + apart * 16) ^ ((grow & 7) << 4);
        s16x8 afrag = *(const s16x8*)(xs + aoff);
#pragma unroll
        for (int ct = 0; ct < 8; ++ct) {
            int brow = ct * 16 + arow;
            int boff = (brow * 256 + ks * 64 + apart * 16) ^ ((brow & 7) << 4);
            s16x8 bfrag = *(const s16x8*)(wt + boff);
            acc[ct] = __builtin_amdgcn_mfma_f32_16x16x32_bf16(afrag, bfrag, acc[ct], 0, 0, 0);
        }
    }
    int orow0 = node0 + w * 16 + apart * 4;
    int ocol = arow;
#pragma unroll
    for (int ct = 0; ct < 8; ++ct) {
#pragma unroll
        for (int r = 0; r < 4; ++r) {
            int g = orow0 + r;
            if (g < N) {
                __half hh = __float2half(acc[ct][r]);
                Hh[(size_t)g * 128 + ct * 16 + ocol] = __half_as_ushort(hh);
            }
        }
    }
}

// fused: out = relu(LN(bias + sum_e ew*H[src])); 4 nodes per wave (16 lanes each),
// degree-ranked assignment via nfo; edata descriptor prefetch one batch ahead.
template <bool FINAL>
__global__ __launch_bounds__(256) void k_agg_ln(const unsigned short* __restrict__ Hh,
                                                const unsigned int* __restrict__ edata,
                                                const uint2* __restrict__ nfo,
                                                const float* __restrict__ bias,
                                                const float* __restrict__ g,
                                                const float* __restrict__ be,
                                                unsigned short* __restrict__ outb,
                                                void* __restrict__ outAny,
                                                const int* __restrict__ flags, int N) {
    int t = threadIdx.x;
    int l16 = t & 15;
    int idx = blockIdx.x * 16 + (t >> 4);
    if (idx >= N) return;
    uint2 info = nfo[idx];
    int base = (int)info.x;
    int deg = (int)(info.y & 0xffffu);
    int node = (idx & ~255) | (int)(info.y >> 16);
    __half2 a01 = u2h2(0u), a23 = u2h2(0u), a45 = u2h2(0u), a67 = u2h2(0u);
    const uint4* Hl = (const uint4*)Hh + l16;   // + (row << 4)
    const uint4* ep = (const uint4*)(edata + base);
    int nb = (deg + 7) >> 3;
    uint4 q0 = make_uint4(0, 0, 0, 0), q1 = q0;
    if (nb > 0) { q0 = ep[0]; q1 = ep[1]; }
    for (int ib = 0; ib < nb; ++ib) {
        uint4 p0 = q0, p1 = q1;
        if (ib + 1 < nb) { p0 = ep[2 * ib + 2]; p1 = ep[2 * ib + 3]; }
        uint4 h0 = Hl[(size_t)(q0.x & 0xffffu) << 4];
        uint4 h1 = Hl[(size_t)(q0.y & 0xffffu) << 4];
        uint4 h2 = Hl[(size_t)(q0.z & 0xffffu) << 4];
        uint4 h3 = Hl[(size_t)(q0.w & 0xffffu) << 4];
        uint4 h4 = Hl[(size_t)(q1.x & 0xffffu) << 4];
        uint4 h5 = Hl[(size_t)(q1.y & 0xffffu) << 4];
        uint4 h6 = Hl[(size_t)(q1.z & 0xffffu) << 4];
        uint4 h7 = Hl[(size_t)(q1.w & 0xffffu) << 4];
        unsigned int wb; __half2 w2;
#define ACC8(hh, wsrc)                                                        \
        wb = (wsrc) >> 16; w2 = u2h2(wb | (wb << 16));                        \
        a01 = __hfma2(u2h2(hh.x), w2, a01); a23 = __hfma2(u2h2(hh.y), w2, a23); \
        a45 = __hfma2(u2h2(hh.z), w2, a45); a67 = __hfma2(u2h2(hh.w), w2, a67);
        ACC8(h0, q0.x) ACC8(h1, q0.y) ACC8(h2, q0.z) ACC8(h3, q0.w)
        ACC8(h4, q1.x) ACC8(h5, q1.y) ACC8(h6, q1.z) ACC8(h7, q1.w)
#undef ACC8
        q0 = p0; q1 = p1;
    }
    float4 bv0 = ((const float4*)bias)[2 * l16];
    float4 bv1 = ((const float4*)bias)[2 * l16 + 1];
    float a0 = __low2float(a01) + bv0.x, a1 = __high2float(a01) + bv0.y;
    float a2 = __low2float(a23) + bv0.z, a3 = __high2float(a23) + bv0.w;
    float a4 = __low2float(a45) + bv1.x, a5 = __high2float(a45) + bv1.y;
    float a6 = __low2float(a67) + bv1.z, a7 = __high2float(a67) + bv1.w;
    // LayerNorm over 128 features spread 8-per-lane across 16 lanes
    float s = ((a0 + a1) + (a2 + a3)) + ((a4 + a5) + (a6 + a7));
#pragma unroll
    for (int m = 8; m >= 1; m >>= 1) s += __shfl_xor(s, m, 64);
    float mu = s * (1.f / 128.f);
    float d0 = a0 - mu, d1 = a1 - mu, d2 = a2 - mu, d3 = a3 - mu;
    float d4 = a4 - mu, d5 = a5 - mu, d6 = a6 - mu, d7 = a7 - mu;
    float q = ((d0 * d0 + d1 * d1) + (d2 * d2 + d3 * d3)) +
              ((d4 * d4 + d5 * d5) + (d6 * d6 + d7 * d7));
#pragma unroll
    for (int m = 8; m >= 1; m >>= 1) q += __shfl_xor(q, m, 64);
    float rs = rsqrtf(q * (1.f / 128.f) + LN_EPS);
    float4 gv0 = ((const float4*)g)[2 * l16], gv1 = ((const float4*)g)[2 * l16 + 1];
    float4 bev0 = ((const float4*)be)[2 * l16], bev1 = ((const float4*)be)[2 * l16 + 1];
    float r0 = fmaxf(d0 * rs * gv0.x + bev0.x, 0.f);
    float r1 = fmaxf(d1 * rs * gv0.y + bev0.y, 0.f);
    float r2 = fmaxf(d2 * rs * gv0.z + bev0.z, 0.f);
    float r3 = fmaxf(d3 * rs * gv0.w + bev0.w, 0.f);
    float r4 = fmaxf(d4 * rs * gv1.x + bev1.x, 0.f);
    float r5 = fmaxf(d5 * rs * gv1.y + bev1.y, 0.f);
    float r6 = fmaxf(d6 * rs * gv1.z + bev1.z, 0.f);
    float r7 = fmaxf(d7 * rs * gv1.w + bev1.w, 0.f);
    if (FINAL) {
        if (flags[0]) {
            float4* o = (float4*)outAny + (size_t)node * 32 + 2 * l16;
            o[0] = make_float4(r0, r1, r2, r3);
            o[1] = make_float4(r4, r5, r6, r7);
        } else {
            uint4 o;
            o.x = pk2(r0, r1); o.y = pk2(r2, r3);
            o.z = pk2(r4, r5); o.w = pk2(r6, r7);
            ((uint4*)outAny)[(size_t)node * 16 + l16] = o;
        }
    } else {
        uint4 o;
        o.x = pk2(r0, r1); o.y = pk2(r2, r3);
        o.z = pk2(r4, r5); o.w = pk2(r6, r7);
        ((uint4*)outb)[(size_t)node * 16 + l16] = o;
    }
}

extern "C" void kernel_launch(void* const* d_in, const int* in_sizes, int n_in,
                              void* d_out, int out_size, void* d_ws, size_t ws_size,
                              hipStream_t stream) {
    const unsigned short* x_u16 = (const unsigned short*)d_in[0];
    const int*            ei    = (const int*)d_in[1];

    const int N = in_sizes[0] / 128;
    const int E = in_sizes[2];
    const int B = (N + 255) >> 8;          // buckets of 256 nodes (<=256)
    const int chunk = (E + G1 - 1) / G1;

    // ---- workspace layout ----
    unsigned short* Xb = (unsigned short*)d_ws;            // N*128 bf16 (mid act)
    unsigned short* Hh = Xb + (size_t)N * 128;             // N*128 f16
    unsigned int* gA    = (unsigned int*)(Hh + (size_t)N * 128); // E
    unsigned int* edata = gA + E;                          // B*CAPB
    unsigned char* g8   = (unsigned char*)(edata + (size_t)B * CAPB); // E (pad 4)
    int* cnt2d  = (int*)(g8 + ((E + 3) & ~3));             // 256*256
    int* lofs2d = cnt2d + 65536;                           // 256*256
    uint2* nfo  = (uint2*)(lofs2d + 65536);                // N
    int* flags  = (int*)(nfo + N);                         // 8
    unsigned short* Wt1 = (unsigned short*)(flags + 8);    // 16384 bf16
    unsigned short* Wt2 = Wt1 + 16384;                     // 16384 bf16
    float* sm   = (float*)(Wt2 + 16384);                   // 6*128 f32
    float* b1f  = sm;
    float* b2f_ = sm + 128;
    float* g1f  = sm + 256;
    float* g2f  = sm + 384;
    float* be1f = sm + 512;
    float* be2f = sm + 640;

    const int nodeBlocks = (N + 15) / 16;
    const int gemmBlocks = (N + 63) / 64;

    // ---- pass1: edge binning + weight prep (merged, 320 blocks) ----
    k_p1<<<G1 + 64, 256, 0, stream>>>(x_u16, ei, d_in[2],
                                      d_in[3], d_in[5], d_in[4], d_in[6],
                                      d_in[7], d_in[9], d_in[8], d_in[10],
                                      Wt1, Wt2, sm,
                                      E, B, chunk, gA, g8, cnt2d, lofs2d, flags);
    k_p3<<<B, 256, 0, stream>>>(gA, g8, cnt2d, lofs2d, edata, nfo, N, B, chunk);

    // ---- layer 1 (GEMM reads d_in[0] directly, converts in staging) ----
    k_gemm<<<gemmBlocks, 256, 0, stream>>>(d_in[0], Wt1, Hh, N, flags, 1);
    k_agg_ln<false><<<nodeBlocks, 256, 0, stream>>>(Hh, edata, nfo, b1f, g1f, be1f, Xb, nullptr, flags, N);

    // ---- layer 2 ----
    k_gemm<<<gemmBlocks, 256, 0, stream>>>(Xb, Wt2, Hh, N, flags, 0);
    k_agg_ln<true><<<nodeBlocks, 256, 0, stream>>>(Hh, edata, nfo, b2f_, g2f, be2f, nullptr, d_out, flags, N);
}

// Round 11
// 109.962 us; speedup vs baseline: 1.1494x; 1.1494x over previous
//
#include <hip/hip_runtime.h>
#include <hip/hip_fp16.h>
#include <stdint.h>

#define LN_EPS 1e-5f
#define G1 256
#define P1CAP 4096
#define P3CAP 6144
#define CAPB 6144

typedef __attribute__((ext_vector_type(8))) short s16x8;
typedef __attribute__((ext_vector_type(4))) float f32x4;

__device__ __forceinline__ float b2f(unsigned short u) {
    union { unsigned int i; float f; } v; v.i = ((unsigned int)u) << 16; return v.f;
}
__device__ __forceinline__ unsigned short f2b(float f) {
    union { float f; unsigned int i; } v; v.f = f;
    unsigned int u = v.i;
    return (unsigned short)((u + 0x7fffu + ((u >> 16) & 1u)) >> 16);
}
__device__ __forceinline__ unsigned int pk2(float a, float b) {
    return (unsigned int)f2b(a) | ((unsigned int)f2b(b) << 16);
}
__device__ __forceinline__ __half2 u2h2(unsigned int u) {
    union { unsigned int i; __half2 h; } v; v.i = u; return v.h;
}

__device__ __forceinline__ float rdf(const void* p, int i, int f32flag) {
    return f32flag ? ((const float*)p)[i] : b2f(((const unsigned short*)p)[i]);
}

// pass 1 (320 blocks): blocks [0,256) bin edges by bucket (dst>>8);
// blocks [256,320) transpose W1/W2 -> bf16 and convert small params.
// Every block locally re-derives dtype flags; block 0 publishes them.
__global__ __launch_bounds__(256) void k_p1(const unsigned short* __restrict__ xu,
                                            const int* __restrict__ ei, const void* __restrict__ ew,
                                            const void* W1, const void* W2,
                                            const void* b1, const void* b2_,
                                            const void* g1, const void* g2,
                                            const void* be1, const void* be2,
                                            unsigned short* __restrict__ Wt1,
                                            unsigned short* __restrict__ Wt2,
                                            float* __restrict__ sm,
                                            int E, int B, int chunk,
                                            unsigned int* __restrict__ gA,
                                            unsigned char* __restrict__ g8,
                                            int* __restrict__ cnt2d, int* __restrict__ lofs2d,
                                            int* __restrict__ flags) {
    __shared__ int hist[256], cur[256], tmp[256];
    __shared__ unsigned int bin32[P1CAP];
    __shared__ unsigned char bin8[P1CAP];
    int t = threadIdx.x, g = blockIdx.x;
    // ---- local dtype detection ----
    if (t < 2) hist[t] = 0;
    __syncthreads();
    int c1 = 0;
    for (int i = t; i < 2048; i += 256)
        if (fabsf(b2f(xu[i])) > 1e6f) ++c1;
    if (c1) atomicAdd(&hist[0], c1);
    int mn = (E < 1024) ? E : 1024;
    int z = 0;
    for (int i = t; i < mn; i += 256)
        if (ei[2 * i + 1] == 0) ++z;
    if (z) atomicAdd(&hist[1], z);
    __syncthreads();
    int f32f = (hist[0] > 32) ? 1 : 0;
    int f64  = (hist[1] > (mn >> 1)) ? 1 : 0;
    if (g == 0 && t == 0) { flags[0] = f32f; flags[1] = f64; }

    if (g >= G1) {
        // ---- prep role ----
        int i = (g - G1) * 256 + t;      // 64*256 = 16384
        int k = i >> 7, j = i & 127;
        Wt1[j * 128 + k] = f2b(rdf(W1, i, f32f));
        Wt2[j * 128 + k] = f2b(rdf(W2, i, f32f));
        if (g == G1 && t < 128) {
            sm[t]       = rdf(b1, t, f32f);
            sm[128 + t] = rdf(b2_, t, f32f);
            sm[256 + t] = rdf(g1, t, f32f);
            sm[384 + t] = rdf(g2, t, f32f);
            sm[512 + t] = rdf(be1, t, f32f);
            sm[640 + t] = rdf(be2, t, f32f);
        }
        return;
    }
    __syncthreads();
    // ---- binning ----
    int base = g * chunk;
    int cnt = E - base; if (cnt > chunk) cnt = chunk; if (cnt < 0) cnt = 0;
    hist[t] = 0;
    __syncthreads();
    for (int i = t; i < cnt; i += 256) {
        int e = base + i;
        int d = f64 ? ei[2 * E + 2 * e] : ei[E + e];
        atomicAdd(&hist[d >> 8], 1);
    }
    __syncthreads();
    int v = hist[t];
    tmp[t] = v;
    __syncthreads();
    for (int d = 1; d < 256; d <<= 1) {
        int x = (t >= d) ? tmp[t - d] : 0;
        __syncthreads();
        tmp[t] += x;
        __syncthreads();
    }
    int excl = tmp[t] - v;
    cur[t] = excl;
    if (t < B) { cnt2d[t * G1 + g] = v; lofs2d[t * G1 + g] = excl; }
    __syncthreads();
    for (int i = t; i < cnt; i += 256) {
        int e = base + i;
        int d, sN;
        if (f64) { d = ei[2 * E + 2 * e]; sN = ei[2 * e]; }
        else     { d = ei[E + e];         sN = ei[e]; }
        float w = f32f ? ((const float*)ew)[e] : b2f(((const unsigned short*)ew)[e]);
        __half wh = __float2half(w);
        int p = atomicAdd(&cur[d >> 8], 1);
        bin32[p] = (unsigned int)(sN & 0xffff) | ((unsigned int)__half_as_ushort(wh) << 16);
        bin8[p]  = (unsigned char)(d & 255);
    }
    __syncthreads();
    for (int j = t; j < cnt; j += 256) {
        gA[base + j] = bin32[j];
        g8[base + j] = bin8[j];
    }
}

// dual-role kernel: blocks [0,B) = pass-3 CSR finalize (direct global scatter);
// blocks [B, B+gemmBlocks) = layer-1 MFMA GEMM. Independent work, one launch.
__global__ __launch_bounds__(256) void k_p3g(const unsigned int* __restrict__ gA,
                                             const unsigned char* __restrict__ g8,
                                             const int* __restrict__ cnt2d,
                                             const int* __restrict__ lofs2d,
                                             unsigned int* __restrict__ edata,
                                             uint2* __restrict__ nfo,
                                             const void* __restrict__ X,
                                             const unsigned short* __restrict__ Wt,
                                             unsigned short* __restrict__ Hh,
                                             const int* __restrict__ flags,
                                             int N, int B, int chunk) {
    __shared__ unsigned char lds[49152];
    int t = threadIdx.x, g = blockIdx.x;

    if (g < B) {
        // ================= pass-3 role (LDS: 24576 raw + 6144 r8 + 2052) ======
        unsigned int* raw = (unsigned int*)lds;
        unsigned char* r8 = lds + 24576;
        int* h   = (int*)(lds + 30720);
        int* tmp = (int*)(lds + 31744);
        int* s_cnt = (int*)(lds + 32768);
        int b = g;
        int segc = cnt2d[b * G1 + t];
        int sbase = t * chunk + lofs2d[b * G1 + t];
        int v = segc;
        tmp[t] = v;
        __syncthreads();
        for (int d = 1; d < 256; d <<= 1) {
            int x = (t >= d) ? tmp[t - d] : 0;
            __syncthreads();
            tmp[t] += x;
            __syncthreads();
        }
        int lo = tmp[t] - v;
        if (t == 255) s_cnt[0] = tmp[255];
        // gather my segment into LDS, 4 independent loads in flight
        int j = 0;
        for (; j + 3 < segc; j += 4) {
            unsigned int a0 = gA[sbase + j], a1 = gA[sbase + j + 1];
            unsigned int a2 = gA[sbase + j + 2], a3 = gA[sbase + j + 3];
            unsigned char c0 = g8[sbase + j], c1 = g8[sbase + j + 1];
            unsigned char c2 = g8[sbase + j + 2], c3 = g8[sbase + j + 3];
            int i0 = lo + j;
            if (i0 + 3 < P3CAP) {
                raw[i0] = a0; raw[i0 + 1] = a1; raw[i0 + 2] = a2; raw[i0 + 3] = a3;
                r8[i0] = c0; r8[i0 + 1] = c1; r8[i0 + 2] = c2; r8[i0 + 3] = c3;
            }
        }
        for (; j < segc; ++j) {
            int idx = lo + j;
            if (idx < P3CAP) { raw[idx] = gA[sbase + j]; r8[idx] = g8[sbase + j]; }
        }
        h[t] = 0;
        __syncthreads();
        int cnt = s_cnt[0]; if (cnt > P3CAP) cnt = P3CAP;
        for (int i = t; i < cnt; i += 256) atomicAdd(&h[r8[i]], 1);
        __syncthreads();
        int deg = h[t];
        int pd = (deg + 7) & ~7;
        tmp[t] = pd;
        __syncthreads();
        for (int d = 1; d < 256; d <<= 1) {
            int x = (t >= d) ? tmp[t - d] : 0;
            __syncthreads();
            tmp[t] += x;
            __syncthreads();
        }
        int pexcl = tmp[t] - pd;
        int padTot = tmp[255]; if (padTot > CAPB) padTot = CAPB;
        int node0 = b << 8;
        int gbase = b * CAPB;
        if (node0 + t < N) nfo[node0 + t] = make_uint2((unsigned)(gbase + pexcl), (unsigned)deg);
        h[t] = pexcl;
        // zero-fill padded region directly in global (block-local 24KB window)
        for (int i = t; i < padTot; i += 256) edata[gbase + i] = 0;
        __syncthreads();
        // scatter directly to global (same window; L2-merged)
        for (int i = t; i < cnt; i += 256) {
            int p = atomicAdd(&h[r8[i]], 1);
            if (p < CAPB) edata[gbase + p] = raw[i];
        }
        return;
    }

    // ================= layer-1 GEMM role =================
    unsigned char* xs = lds;
    unsigned char* wt = lds + 16384;
    int node0 = (g - B) * 64;
    int f32in = flags[0];

#pragma unroll
    for (int it = 0; it < 8; ++it) {
        int c = t + it * 256;
        int row = c >> 4, cc = c & 15;
        uint4 v = *(const uint4*)(Wt + row * 128 + cc * 8);
        int off = (row * 256 + cc * 16) ^ ((row & 7) << 4);
        *(uint4*)(wt + off) = v;
    }
#pragma unroll
    for (int it = 0; it < 4; ++it) {
        int c = t + it * 256;
        int row = c >> 4, cc = c & 15;
        int gg = node0 + row;
        uint4 v = make_uint4(0, 0, 0, 0);
        if (gg < N) {
            if (f32in) {
                const float* xr = (const float*)X + (size_t)gg * 128 + cc * 8;
                float4 f0 = *(const float4*)xr;
                float4 f1 = *(const float4*)(xr + 4);
                v.x = pk2(f0.x, f0.y); v.y = pk2(f0.z, f0.w);
                v.z = pk2(f1.x, f1.y); v.w = pk2(f1.z, f1.w);
            } else {
                v = *(const uint4*)((const unsigned short*)X + (size_t)gg * 128 + cc * 8);
            }
        }
        int off = (row * 256 + cc * 16) ^ ((row & 7) << 4);
        *(uint4*)(xs + off) = v;
    }
    __syncthreads();

    int w = t >> 6, l = t & 63;
    int arow = l & 15;
    int apart = l >> 4;
    f32x4 acc[8];
#pragma unroll
    for (int ct = 0; ct < 8; ++ct) acc[ct] = (f32x4){0.f, 0.f, 0.f, 0.f};

#pragma unroll
    for (int ks = 0; ks < 4; ++ks) {
        int grow = w * 16 + arow;
        int aoff = (grow * 256 + ks * 64 + apart * 16) ^ ((grow & 7) << 4);
        s16x8 afrag = *(const s16x8*)(xs + aoff);
#pragma unroll
        for (int ct = 0; ct < 8; ++ct) {
            int brow = ct * 16 + arow;
            int boff = (brow * 256 + ks * 64 + apart * 16) ^ ((brow & 7) << 4);
            s16x8 bfrag = *(const s16x8*)(wt + boff);
            acc[ct] = __builtin_amdgcn_mfma_f32_16x16x32_bf16(afrag, bfrag, acc[ct], 0, 0, 0);
        }
    }
    int orow0 = node0 + w * 16 + apart * 4;
    int ocol = arow;
#pragma unroll
    for (int ct = 0; ct < 8; ++ct) {
#pragma unroll
        for (int r = 0; r < 4; ++r) {
            int gg = orow0 + r;
            if (gg < N) {
                __half hh = __float2half(acc[ct][r]);
                Hh[(size_t)gg * 128 + ct * 16 + ocol] = __half_as_ushort(hh);
            }
        }
    }
}

// MFMA bf16 GEMM (layer 2 standalone): X is bf16 workspace.
__global__ __launch_bounds__(256) void k_gemm(const unsigned short* __restrict__ X,
                                              const unsigned short* __restrict__ Wt,
                                              unsigned short* __restrict__ Hh, int N) {
    __shared__ unsigned char lds[49152];
    unsigned char* xs = lds;
    unsigned char* wt = lds + 16384;
    int t = threadIdx.x;
    int node0 = blockIdx.x * 64;

#pragma unroll
    for (int it = 0; it < 8; ++it) {
        int c = t + it * 256;
        int row = c >> 4, cc = c & 15;
        uint4 v = *(const uint4*)(Wt + row * 128 + cc * 8);
        int off = (row * 256 + cc * 16) ^ ((row & 7) << 4);
        *(uint4*)(wt + off) = v;
    }
#pragma unroll
    for (int it = 0; it < 4; ++it) {
        int c = t + it * 256;
        int row = c >> 4, cc = c & 15;
        int g = node0 + row;
        uint4 v = make_uint4(0, 0, 0, 0);
        if (g < N) v = *(const uint4*)(X + (size_t)g * 128 + cc * 8);
        int off = (row * 256 + cc * 16) ^ ((row & 7) << 4);
        *(uint4*)(xs + off) = v;
    }
    __syncthreads();

    int w = t >> 6, l = t & 63;
    int arow = l & 15;
    int apart = l >> 4;
    f32x4 acc[8];
#pragma unroll
    for (int ct = 0; ct < 8; ++ct) acc[ct] = (f32x4){0.f, 0.f, 0.f, 0.f};

#pragma unroll
    for (int ks = 0; ks < 4; ++ks) {
        int grow = w * 16 + arow;
        int aoff = (grow * 256 + ks * 64 + apart * 16) ^ ((grow & 7) << 4);
        s16x8 afrag = *(const s16x8*)(xs + aoff);
#pragma unroll
        for (int ct = 0; ct < 8; ++ct) {
            int brow = ct * 16 + arow;
            int boff = (brow * 256 + ks * 64 + apart * 16) ^ ((brow & 7) << 4);
            s16x8 bfrag = *(const s16x8*)(wt + boff);
            acc[ct] = __builtin_amdgcn_mfma_f32_16x16x32_bf16(afrag, bfrag, acc[ct], 0, 0, 0);
        }
    }
    int orow0 = node0 + w * 16 + apart * 4;
    int ocol = arow;
#pragma unroll
    for (int ct = 0; ct < 8; ++ct) {
#pragma unroll
        for (int r = 0; r < 4; ++r) {
            int g = orow0 + r;
            if (g < N) {
                __half hh = __float2half(acc[ct][r]);
                Hh[(size_t)g * 128 + ct * 16 + ocol] = __half_as_ushort(hh);
            }
        }
    }
}

// fused: out = relu(LN(bias + sum_e ew*H[src])); 4 nodes per wave (16 lanes each).
// lane owns features 8*l16 .. 8*l16+7 (one uint4 = full row slice per edge).
template <bool FINAL>
__global__ __launch_bounds__(256) void k_agg_ln(const unsigned short* __restrict__ Hh,
                                                const unsigned int* __restrict__ edata,
                                                const uint2* __restrict__ nfo,
                                                const float* __restrict__ bias,
                                                const float* __restrict__ g,
                                                const float* __restrict__ be,
                                                unsigned short* __restrict__ outb,
                                                void* __restrict__ outAny,
                                                const int* __restrict__ flags, int N) {
    int t = threadIdx.x;
    int l16 = t & 15;
    int node = blockIdx.x * 16 + (t >> 4);
    if (node >= N) return;
    uint2 info = nfo[node];
    int base = (int)info.x, deg = (int)info.y;
    __half2 a01 = u2h2(0u), a23 = u2h2(0u), a45 = u2h2(0u), a67 = u2h2(0u);
    const uint4* Hl = (const uint4*)Hh + l16;   // + (row << 4)
    for (int b0 = 0; b0 < deg; b0 += 8) {
        const uint4* ep = (const uint4*)(edata + base + b0);
        uint4 q0 = ep[0], q1 = ep[1];
        uint4 h0 = Hl[(size_t)(q0.x & 0xffffu) << 4];
        uint4 h1 = Hl[(size_t)(q0.y & 0xffffu) << 4];
        uint4 h2 = Hl[(size_t)(q0.z & 0xffffu) << 4];
        uint4 h3 = Hl[(size_t)(q0.w & 0xffffu) << 4];
        uint4 h4 = Hl[(size_t)(q1.x & 0xffffu) << 4];
        uint4 h5 = Hl[(size_t)(q1.y & 0xffffu) << 4];
        uint4 h6 = Hl[(size_t)(q1.z & 0xffffu) << 4];
        uint4 h7 = Hl[(size_t)(q1.w & 0xffffu) << 4];
        unsigned int wb; __half2 w2;
#define ACC8(hh, wsrc)                                                        \
        wb = (wsrc) >> 16; w2 = u2h2(wb | (wb << 16));                        \
        a01 = __hfma2(u2h2(hh.x), w2, a01); a23 = __hfma2(u2h2(hh.y), w2, a23); \
        a45 = __hfma2(u2h2(hh.z), w2, a45); a67 = __hfma2(u2h2(hh.w), w2, a67);
        ACC8(h0, q0.x) ACC8(h1, q0.y) ACC8(h2, q0.z) ACC8(h3, q0.w)
        ACC8(h4, q1.x) ACC8(h5, q1.y) ACC8(h6, q1.z) ACC8(h7, q1.w)
#undef ACC8
    }
    float4 bv0 = ((const float4*)bias)[2 * l16];
    float4 bv1 = ((const float4*)bias)[2 * l16 + 1];
    float a0 = __low2float(a01) + bv0.x, a1 = __high2float(a01) + bv0.y;
    float a2 = __low2float(a23) + bv0.z, a3 = __high2float(a23) + bv0.w;
    float a4 = __low2float(a45) + bv1.x, a5 = __high2float(a45) + bv1.y;
    float a6 = __low2float(a67) + bv1.z, a7 = __high2float(a67) + bv1.w;
    // LayerNorm over 128 features spread 8-per-lane across 16 lanes
    float s = ((a0 + a1) + (a2 + a3)) + ((a4 + a5) + (a6 + a7));
#pragma unroll
    for (int m = 8; m >= 1; m >>= 1) s += __shfl_xor(s, m, 64);
    float mu = s * (1.f / 128.f);
    float d0 = a0 - mu, d1 = a1 - mu, d2 = a2 - mu, d3 = a3 - mu;
    float d4 = a4 - mu, d5 = a5 - mu, d6 = a6 - mu, d7 = a7 - mu;
    float q = ((d0 * d0 + d1 * d1) + (d2 * d2 + d3 * d3)) +
              ((d4 * d4 + d5 * d5) + (d6 * d6 + d7 * d7));
#pragma unroll
    for (int m = 8; m >= 1; m >>= 1) q += __shfl_xor(q, m, 64);
    float rs = rsqrtf(q * (1.f / 128.f) + LN_EPS);
    float4 gv0 = ((const float4*)g)[2 * l16], gv1 = ((const float4*)g)[2 * l16 + 1];
    float4 bev0 = ((const float4*)be)[2 * l16], bev1 = ((const float4*)be)[2 * l16 + 1];
    float r0 = fmaxf(d0 * rs * gv0.x + bev0.x, 0.f);
    float r1 = fmaxf(d1 * rs * gv0.y + bev0.y, 0.f);
    float r2 = fmaxf(d2 * rs * gv0.z + bev0.z, 0.f);
    float r3 = fmaxf(d3 * rs * gv0.w + bev0.w, 0.f);
    float r4 = fmaxf(d4 * rs * gv1.x + bev1.x, 0.f);
    float r5 = fmaxf(d5 * rs * gv1.y + bev1.y, 0.f);
    float r6 = fmaxf(d6 * rs * gv1.z + bev1.z, 0.f);
    float r7 = fmaxf(d7 * rs * gv1.w + bev1.w, 0.f);
    if (FINAL) {
        if (flags[0]) {
            float4* o = (float4*)outAny + (size_t)node * 32 + 2 * l16;
            o[0] = make_float4(r0, r1, r2, r3);
            o[1] = make_float4(r4, r5, r6, r7);
        } else {
            uint4 o;
            o.x = pk2(r0, r1); o.y = pk2(r2, r3);
            o.z = pk2(r4, r5); o.w = pk2(r6, r7);
            ((uint4*)outAny)[(size_t)node * 16 + l16] = o;
        }
    } else {
        uint4 o;
        o.x = pk2(r0, r1); o.y = pk2(r2, r3);
        o.z = pk2(r4, r5); o.w = pk2(r6, r7);
        ((uint4*)outb)[(size_t)node * 16 + l16] = o;
    }
}

extern "C" void kernel_launch(void* const* d_in, const int* in_sizes, int n_in,
                              void* d_out, int out_size, void* d_ws, size_t ws_size,
                              hipStream_t stream) {
    const unsigned short* x_u16 = (const unsigned short*)d_in[0];
    const int*            ei    = (const int*)d_in[1];

    const int N = in_sizes[0] / 128;
    const int E = in_sizes[2];
    const int B = (N + 255) >> 8;          // buckets of 256 nodes (<=256)
    const int chunk = (E + G1 - 1) / G1;

    // ---- workspace layout ----
    unsigned short* Xb = (unsigned short*)d_ws;            // N*128 bf16 (mid act)
    unsigned short* Hh = Xb + (size_t)N * 128;             // N*128 f16
    unsigned int* gA    = (unsigned int*)(Hh + (size_t)N * 128); // E
    unsigned int* edata = gA + E;                          // B*CAPB
    unsigned char* g8   = (unsigned char*)(edata + (size_t)B * CAPB); // E (pad 4)
    int* cnt2d  = (int*)(g8 + ((E + 3) & ~3));             // 256*256
    int* lofs2d = cnt2d + 65536;                           // 256*256
    uint2* nfo  = (uint2*)(lofs2d + 65536);                // N
    int* flags  = (int*)(nfo + N);                         // 8
    unsigned short* Wt1 = (unsigned short*)(flags + 8);    // 16384 bf16
    unsigned short* Wt2 = Wt1 + 16384;                     // 16384 bf16
    float* sm   = (float*)(Wt2 + 16384);                   // 6*128 f32
    float* b1f  = sm;
    float* b2f_ = sm + 128;
    float* g1f  = sm + 256;
    float* g2f  = sm + 384;
    float* be1f = sm + 512;
    float* be2f = sm + 640;

    const int nodeBlocks = (N + 15) / 16;
    const int gemmBlocks = (N + 63) / 64;

    // ---- pass1: edge binning + weight prep (merged, 320 blocks) ----
    k_p1<<<G1 + 64, 256, 0, stream>>>(x_u16, ei, d_in[2],
                                      d_in[3], d_in[5], d_in[4], d_in[6],
                                      d_in[7], d_in[9], d_in[8], d_in[10],
                                      Wt1, Wt2, sm,
                                      E, B, chunk, gA, g8, cnt2d, lofs2d, flags);

    // ---- pass3 CSR finalize + layer-1 GEMM (merged, independent roles) ----
    k_p3g<<<B + gemmBlocks, 256, 0, stream>>>(gA, g8, cnt2d, lofs2d, edata, nfo,
                                              d_in[0], Wt1, Hh, flags, N, B, chunk);

    // ---- layer 1 aggregate + LN + ReLU ----
    k_agg_ln<false><<<nodeBlocks, 256, 0, stream>>>(Hh, edata, nfo, b1f, g1f, be1f, Xb, nullptr, flags, N);

    // ---- layer 2 ----
    k_gemm<<<gemmBlocks, 256, 0, stream>>>(Xb, Wt2, Hh, N);
    k_agg_ln<true><<<nodeBlocks, 256, 0, stream>>>(Hh, edata, nfo, b2f_, g2f, be2f, nullptr, d_out, flags, N);
}

// Round 12
// 99.888 us; speedup vs baseline: 1.2654x; 1.1008x over previous
//
#include <hip/hip_runtime.h>
#include <hip/hip_fp16.h>
#include <stdint.h>

#define LN_EPS 1e-5f
#define G1 256
#define P1CAP 4096
#define P3CAP 6144
#define CAPB 6144

typedef __attribute__((ext_vector_type(8))) short s16x8;
typedef __attribute__((ext_vector_type(4))) float f32x4;

__device__ __forceinline__ float b2f(unsigned short u) {
    union { unsigned int i; float f; } v; v.i = ((unsigned int)u) << 16; return v.f;
}
__device__ __forceinline__ unsigned short f2b(float f) {
    union { float f; unsigned int i; } v; v.f = f;
    unsigned int u = v.i;
    return (unsigned short)((u + 0x7fffu + ((u >> 16) & 1u)) >> 16);
}
__device__ __forceinline__ unsigned int pk2(float a, float b) {
    return (unsigned int)f2b(a) | ((unsigned int)f2b(b) << 16);
}
__device__ __forceinline__ __half2 u2h2(unsigned int u) {
    union { unsigned int i; __half2 h; } v; v.i = u; return v.h;
}

__device__ __forceinline__ float rdf(const void* p, int i, int f32flag) {
    return f32flag ? ((const float*)p)[i] : b2f(((const unsigned short*)p)[i]);
}

// pass 1 (320 blocks): blocks [0,256) bin edges by bucket (dst>>8);
// blocks [256,320) transpose W1/W2 -> bf16 and convert small params.
__global__ __launch_bounds__(256) void k_p1(const unsigned short* __restrict__ xu,
                                            const int* __restrict__ ei, const void* __restrict__ ew,
                                            const void* W1, const void* W2,
                                            const void* b1, const void* b2_,
                                            const void* g1, const void* g2,
                                            const void* be1, const void* be2,
                                            unsigned short* __restrict__ Wt1,
                                            unsigned short* __restrict__ Wt2,
                                            float* __restrict__ sm,
                                            int E, int B, int chunk,
                                            unsigned int* __restrict__ gA,
                                            unsigned char* __restrict__ g8,
                                            int* __restrict__ cnt2d, int* __restrict__ lofs2d,
                                            int* __restrict__ flags) {
    __shared__ int hist[256], cur[256], tmp[256];
    __shared__ unsigned int bin32[P1CAP];
    __shared__ unsigned char bin8[P1CAP];
    int t = threadIdx.x, g = blockIdx.x;
    // ---- local dtype detection ----
    if (t < 2) hist[t] = 0;
    __syncthreads();
    int c1 = 0;
    for (int i = t; i < 2048; i += 256)
        if (fabsf(b2f(xu[i])) > 1e6f) ++c1;
    if (c1) atomicAdd(&hist[0], c1);
    int mn = (E < 1024) ? E : 1024;
    int z = 0;
    for (int i = t; i < mn; i += 256)
        if (ei[2 * i + 1] == 0) ++z;
    if (z) atomicAdd(&hist[1], z);
    __syncthreads();
    int f32f = (hist[0] > 32) ? 1 : 0;
    int f64  = (hist[1] > (mn >> 1)) ? 1 : 0;
    if (g == 0 && t == 0) { flags[0] = f32f; flags[1] = f64; }

    if (g >= G1) {
        int i = (g - G1) * 256 + t;      // 64*256 = 16384
        int k = i >> 7, j = i & 127;
        Wt1[j * 128 + k] = f2b(rdf(W1, i, f32f));
        Wt2[j * 128 + k] = f2b(rdf(W2, i, f32f));
        if (g == G1 && t < 128) {
            sm[t]       = rdf(b1, t, f32f);
            sm[128 + t] = rdf(b2_, t, f32f);
            sm[256 + t] = rdf(g1, t, f32f);
            sm[384 + t] = rdf(g2, t, f32f);
            sm[512 + t] = rdf(be1, t, f32f);
            sm[640 + t] = rdf(be2, t, f32f);
        }
        return;
    }
    __syncthreads();
    // ---- binning ----
    int base = g * chunk;
    int cnt = E - base; if (cnt > chunk) cnt = chunk; if (cnt < 0) cnt = 0;
    hist[t] = 0;
    __syncthreads();
    for (int i = t; i < cnt; i += 256) {
        int e = base + i;
        int d = f64 ? ei[2 * E + 2 * e] : ei[E + e];
        atomicAdd(&hist[d >> 8], 1);
    }
    __syncthreads();
    int v = hist[t];
    tmp[t] = v;
    __syncthreads();
    for (int d = 1; d < 256; d <<= 1) {
        int x = (t >= d) ? tmp[t - d] : 0;
        __syncthreads();
        tmp[t] += x;
        __syncthreads();
    }
    int excl = tmp[t] - v;
    cur[t] = excl;
    if (t < B) { cnt2d[t * G1 + g] = v; lofs2d[t * G1 + g] = excl; }
    __syncthreads();
    for (int i = t; i < cnt; i += 256) {
        int e = base + i;
        int d, sN;
        if (f64) { d = ei[2 * E + 2 * e]; sN = ei[2 * e]; }
        else     { d = ei[E + e];         sN = ei[e]; }
        float w = f32f ? ((const float*)ew)[e] : b2f(((const unsigned short*)ew)[e]);
        __half wh = __float2half(w);
        int p = atomicAdd(&cur[d >> 8], 1);
        bin32[p] = (unsigned int)(sN & 0xffff) | ((unsigned int)__half_as_ushort(wh) << 16);
        bin8[p]  = (unsigned char)(d & 255);
    }
    __syncthreads();
    for (int j = t; j < cnt; j += 256) {
        gA[base + j] = bin32[j];
        g8[base + j] = bin8[j];
    }
}

// dual-role kernel: blocks [0,B) = pass-3 CSR finalize (direct global scatter);
// blocks [B, B+gemmBlocks) = layer-1 MFMA GEMM.
__global__ __launch_bounds__(256) void k_p3g(const unsigned int* __restrict__ gA,
                                             const unsigned char* __restrict__ g8,
                                             const int* __restrict__ cnt2d,
                                             const int* __restrict__ lofs2d,
                                             unsigned int* __restrict__ edata,
                                             uint2* __restrict__ nfo,
                                             const void* __restrict__ X,
                                             const unsigned short* __restrict__ Wt,
                                             unsigned short* __restrict__ Hh,
                                             const int* __restrict__ flags,
                                             int N, int B, int chunk) {
    __shared__ unsigned char lds[49152];
    int t = threadIdx.x, g = blockIdx.x;

    if (g < B) {
        unsigned int* raw = (unsigned int*)lds;
        unsigned char* r8 = lds + 24576;
        int* h   = (int*)(lds + 30720);
        int* tmp = (int*)(lds + 31744);
        int* s_cnt = (int*)(lds + 32768);
        int b = g;
        int segc = cnt2d[b * G1 + t];
        int sbase = t * chunk + lofs2d[b * G1 + t];
        int v = segc;
        tmp[t] = v;
        __syncthreads();
        for (int d = 1; d < 256; d <<= 1) {
            int x = (t >= d) ? tmp[t - d] : 0;
            __syncthreads();
            tmp[t] += x;
            __syncthreads();
        }
        int lo = tmp[t] - v;
        if (t == 255) s_cnt[0] = tmp[255];
        int j = 0;
        for (; j + 3 < segc; j += 4) {
            unsigned int a0 = gA[sbase + j], a1 = gA[sbase + j + 1];
            unsigned int a2 = gA[sbase + j + 2], a3 = gA[sbase + j + 3];
            unsigned char c0 = g8[sbase + j], c1 = g8[sbase + j + 1];
            unsigned char c2 = g8[sbase + j + 2], c3 = g8[sbase + j + 3];
            int i0 = lo + j;
            if (i0 + 3 < P3CAP) {
                raw[i0] = a0; raw[i0 + 1] = a1; raw[i0 + 2] = a2; raw[i0 + 3] = a3;
                r8[i0] = c0; r8[i0 + 1] = c1; r8[i0 + 2] = c2; r8[i0 + 3] = c3;
            }
        }
        for (; j < segc; ++j) {
            int idx = lo + j;
            if (idx < P3CAP) { raw[idx] = gA[sbase + j]; r8[idx] = g8[sbase + j]; }
        }
        h[t] = 0;
        __syncthreads();
        int cnt = s_cnt[0]; if (cnt > P3CAP) cnt = P3CAP;
        for (int i = t; i < cnt; i += 256) atomicAdd(&h[r8[i]], 1);
        __syncthreads();
        int deg = h[t];
        int pd = (deg + 7) & ~7;
        tmp[t] = pd;
        __syncthreads();
        for (int d = 1; d < 256; d <<= 1) {
            int x = (t >= d) ? tmp[t - d] : 0;
            __syncthreads();
            tmp[t] += x;
            __syncthreads();
        }
        int pexcl = tmp[t] - pd;
        int padTot = tmp[255]; if (padTot > CAPB) padTot = CAPB;
        int node0 = b << 8;
        int gbase = b * CAPB;
        if (node0 + t < N) nfo[node0 + t] = make_uint2((unsigned)(gbase + pexcl), (unsigned)deg);
        h[t] = pexcl;
        for (int i = t; i < padTot; i += 256) edata[gbase + i] = 0;
        __syncthreads();
        for (int i = t; i < cnt; i += 256) {
            int p = atomicAdd(&h[r8[i]], 1);
            if (p < CAPB) edata[gbase + p] = raw[i];
        }
        return;
    }

    // ================= layer-1 GEMM role =================
    unsigned char* xs = lds;
    unsigned char* wt = lds + 16384;
    int node0 = (g - B) * 64;
    int f32in = flags[0];

#pragma unroll
    for (int it = 0; it < 8; ++it) {
        int c = t + it * 256;
        int row = c >> 4, cc = c & 15;
        uint4 v = *(const uint4*)(Wt + row * 128 + cc * 8);
        int off = (row * 256 + cc * 16) ^ ((row & 7) << 4);
        *(uint4*)(wt + off) = v;
    }
#pragma unroll
    for (int it = 0; it < 4; ++it) {
        int c = t + it * 256;
        int row = c >> 4, cc = c & 15;
        int gg = node0 + row;
        uint4 v = make_uint4(0, 0, 0, 0);
        if (gg < N) {
            if (f32in) {
                const float* xr = (const float*)X + (size_t)gg * 128 + cc * 8;
                float4 f0 = *(const float4*)xr;
                float4 f1 = *(const float4*)(xr + 4);
                v.x = pk2(f0.x, f0.y); v.y = pk2(f0.z, f0.w);
                v.z = pk2(f1.x, f1.y); v.w = pk2(f1.z, f1.w);
            } else {
                v = *(const uint4*)((const unsigned short*)X + (size_t)gg * 128 + cc * 8);
            }
        }
        int off = (row * 256 + cc * 16) ^ ((row & 7) << 4);
        *(uint4*)(xs + off) = v;
    }
    __syncthreads();

    int w = t >> 6, l = t & 63;
    int arow = l & 15;
    int apart = l >> 4;
    f32x4 acc[8];
#pragma unroll
    for (int ct = 0; ct < 8; ++ct) acc[ct] = (f32x4){0.f, 0.f, 0.f, 0.f};

#pragma unroll
    for (int ks = 0; ks < 4; ++ks) {
        int grow = w * 16 + arow;
        int aoff = (grow * 256 + ks * 64 + apart * 16) ^ ((grow & 7) << 4);
        s16x8 afrag = *(const s16x8*)(xs + aoff);
#pragma unroll
        for (int ct = 0; ct < 8; ++ct) {
            int brow = ct * 16 + arow;
            int boff = (brow * 256 + ks * 64 + apart * 16) ^ ((brow & 7) << 4);
            s16x8 bfrag = *(const s16x8*)(wt + boff);
            acc[ct] = __builtin_amdgcn_mfma_f32_16x16x32_bf16(afrag, bfrag, acc[ct], 0, 0, 0);
        }
    }
    int orow0 = node0 + w * 16 + apart * 4;
    int ocol = arow;
#pragma unroll
    for (int ct = 0; ct < 8; ++ct) {
#pragma unroll
        for (int r = 0; r < 4; ++r) {
            int gg = orow0 + r;
            if (gg < N) {
                __half hh = __float2half(acc[ct][r]);
                Hh[(size_t)gg * 128 + ct * 16 + ocol] = __half_as_ushort(hh);
            }
        }
    }
}

// fused: agg layer-1 + LN + ReLU + (x W2) MFMA -> Hh2 (f16).
// 16 nodes/block (16 lanes each, 8 feats/lane); post-LN rows staged in LDS.
__global__ __launch_bounds__(256) void k_agg_gemm(const unsigned short* __restrict__ Hh,
                                                  const unsigned int* __restrict__ edata,
                                                  const uint2* __restrict__ nfo,
                                                  const float* __restrict__ bias,
                                                  const float* __restrict__ g,
                                                  const float* __restrict__ be,
                                                  const unsigned short* __restrict__ W2t,
                                                  unsigned short* __restrict__ Hh2,
                                                  int N) {
    __shared__ unsigned char lds[36864];   // wt 32KB + xs 4KB
    unsigned char* wt = lds;
    unsigned char* xs = lds + 32768;
    int t = threadIdx.x;
    int node0 = blockIdx.x * 16;
    // stage W2t (bf16 [j][k], swizzled)
#pragma unroll
    for (int it = 0; it < 8; ++it) {
        int c = t + it * 256;
        int row = c >> 4, cc = c & 15;
        uint4 v = *(const uint4*)(W2t + row * 128 + cc * 8);
        int off = (row * 256 + cc * 16) ^ ((row & 7) << 4);
        *(uint4*)(wt + off) = v;
    }
    // ---- aggregate + LN + ReLU phase ----
    int l16 = t & 15;
    int nodeLocal = t >> 4;
    int node = node0 + nodeLocal;
    uint4 xv = make_uint4(0, 0, 0, 0);
    if (node < N) {
        uint2 info = nfo[node];
        int base = (int)info.x, deg = (int)info.y;
        __half2 a01 = u2h2(0u), a23 = u2h2(0u), a45 = u2h2(0u), a67 = u2h2(0u);
        const uint4* Hl = (const uint4*)Hh + l16;
        for (int b0 = 0; b0 < deg; b0 += 8) {
            const uint4* ep = (const uint4*)(edata + base + b0);
            uint4 q0 = ep[0], q1 = ep[1];
            uint4 h0 = Hl[(size_t)(q0.x & 0xffffu) << 4];
            uint4 h1 = Hl[(size_t)(q0.y & 0xffffu) << 4];
            uint4 h2 = Hl[(size_t)(q0.z & 0xffffu) << 4];
            uint4 h3 = Hl[(size_t)(q0.w & 0xffffu) << 4];
            uint4 h4 = Hl[(size_t)(q1.x & 0xffffu) << 4];
            uint4 h5 = Hl[(size_t)(q1.y & 0xffffu) << 4];
            uint4 h6 = Hl[(size_t)(q1.z & 0xffffu) << 4];
            uint4 h7 = Hl[(size_t)(q1.w & 0xffffu) << 4];
            unsigned int wb; __half2 w2;
#define ACC8(hh, wsrc)                                                        \
            wb = (wsrc) >> 16; w2 = u2h2(wb | (wb << 16));                    \
            a01 = __hfma2(u2h2(hh.x), w2, a01); a23 = __hfma2(u2h2(hh.y), w2, a23); \
            a45 = __hfma2(u2h2(hh.z), w2, a45); a67 = __hfma2(u2h2(hh.w), w2, a67);
            ACC8(h0, q0.x) ACC8(h1, q0.y) ACC8(h2, q0.z) ACC8(h3, q0.w)
            ACC8(h4, q1.x) ACC8(h5, q1.y) ACC8(h6, q1.z) ACC8(h7, q1.w)
#undef ACC8
        }
        float4 bv0 = ((const float4*)bias)[2 * l16];
        float4 bv1 = ((const float4*)bias)[2 * l16 + 1];
        float a0 = __low2float(a01) + bv0.x, a1 = __high2float(a01) + bv0.y;
        float a2 = __low2float(a23) + bv0.z, a3 = __high2float(a23) + bv0.w;
        float a4 = __low2float(a45) + bv1.x, a5 = __high2float(a45) + bv1.y;
        float a6 = __low2float(a67) + bv1.z, a7 = __high2float(a67) + bv1.w;
        float s = ((a0 + a1) + (a2 + a3)) + ((a4 + a5) + (a6 + a7));
#pragma unroll
        for (int m = 8; m >= 1; m >>= 1) s += __shfl_xor(s, m, 64);
        float mu = s * (1.f / 128.f);
        float d0 = a0 - mu, d1 = a1 - mu, d2 = a2 - mu, d3 = a3 - mu;
        float d4 = a4 - mu, d5 = a5 - mu, d6 = a6 - mu, d7 = a7 - mu;
        float q = ((d0 * d0 + d1 * d1) + (d2 * d2 + d3 * d3)) +
                  ((d4 * d4 + d5 * d5) + (d6 * d6 + d7 * d7));
#pragma unroll
        for (int m = 8; m >= 1; m >>= 1) q += __shfl_xor(q, m, 64);
        float rs = rsqrtf(q * (1.f / 128.f) + LN_EPS);
        float4 gv0 = ((const float4*)g)[2 * l16], gv1 = ((const float4*)g)[2 * l16 + 1];
        float4 bev0 = ((const float4*)be)[2 * l16], bev1 = ((const float4*)be)[2 * l16 + 1];
        float r0 = fmaxf(d0 * rs * gv0.x + bev0.x, 0.f);
        float r1 = fmaxf(d1 * rs * gv0.y + bev0.y, 0.f);
        float r2 = fmaxf(d2 * rs * gv0.z + bev0.z, 0.f);
        float r3 = fmaxf(d3 * rs * gv0.w + bev0.w, 0.f);
        float r4 = fmaxf(d4 * rs * gv1.x + bev1.x, 0.f);
        float r5 = fmaxf(d5 * rs * gv1.y + bev1.y, 0.f);
        float r6 = fmaxf(d6 * rs * gv1.z + bev1.z, 0.f);
        float r7 = fmaxf(d7 * rs * gv1.w + bev1.w, 0.f);
        xv.x = pk2(r0, r1); xv.y = pk2(r2, r3);
        xv.z = pk2(r4, r5); xv.w = pk2(r6, r7);
    }
    // stage post-LN row (bf16, swizzled): row = nodeLocal, col chunk = l16
    {
        int off = (nodeLocal * 256 + l16 * 16) ^ ((nodeLocal & 7) << 4);
        *(uint4*)(xs + off) = xv;
    }
    __syncthreads();
    // ---- MFMA phase: 16 rows x 128 cols; wave w covers cols w*32..w*32+31 ----
    int w = t >> 6, l = t & 63;
    int arow = l & 15;
    int apart = l >> 4;
    f32x4 acc[2];
    acc[0] = (f32x4){0.f, 0.f, 0.f, 0.f};
    acc[1] = (f32x4){0.f, 0.f, 0.f, 0.f};
#pragma unroll
    for (int ks = 0; ks < 4; ++ks) {
        int aoff = (arow * 256 + ks * 64 + apart * 16) ^ ((arow & 7) << 4);
        s16x8 afrag = *(const s16x8*)(xs + aoff);
#pragma unroll
        for (int ct2 = 0; ct2 < 2; ++ct2) {
            int ct = w * 2 + ct2;
            int brow = ct * 16 + arow;
            int boff = (brow * 256 + ks * 64 + apart * 16) ^ ((brow & 7) << 4);
            s16x8 bfrag = *(const s16x8*)(wt + boff);
            acc[ct2] = __builtin_amdgcn_mfma_f32_16x16x32_bf16(afrag, bfrag, acc[ct2], 0, 0, 0);
        }
    }
    int orow0 = node0 + apart * 4;
#pragma unroll
    for (int ct2 = 0; ct2 < 2; ++ct2) {
        int ocol = (w * 2 + ct2) * 16 + arow;
#pragma unroll
        for (int r = 0; r < 4; ++r) {
            int gg = orow0 + r;
            if (gg < N) {
                __half hh = __float2half(acc[ct2][r]);
                Hh2[(size_t)gg * 128 + ocol] = __half_as_ushort(hh);
            }
        }
    }
}

// final: out = relu(LN(bias + sum_e ew*H[src])); 4 nodes per wave (16 lanes each).
__global__ __launch_bounds__(256) void k_agg_ln(const unsigned short* __restrict__ Hh,
                                                const unsigned int* __restrict__ edata,
                                                const uint2* __restrict__ nfo,
                                                const float* __restrict__ bias,
                                                const float* __restrict__ g,
                                                const float* __restrict__ be,
                                                void* __restrict__ outAny,
                                                const int* __restrict__ flags, int N) {
    int t = threadIdx.x;
    int l16 = t & 15;
    int node = blockIdx.x * 16 + (t >> 4);
    if (node >= N) return;
    uint2 info = nfo[node];
    int base = (int)info.x, deg = (int)info.y;
    __half2 a01 = u2h2(0u), a23 = u2h2(0u), a45 = u2h2(0u), a67 = u2h2(0u);
    const uint4* Hl = (const uint4*)Hh + l16;
    for (int b0 = 0; b0 < deg; b0 += 8) {
        const uint4* ep = (const uint4*)(edata + base + b0);
        uint4 q0 = ep[0], q1 = ep[1];
        uint4 h0 = Hl[(size_t)(q0.x & 0xffffu) << 4];
        uint4 h1 = Hl[(size_t)(q0.y & 0xffffu) << 4];
        uint4 h2 = Hl[(size_t)(q0.z & 0xffffu) << 4];
        uint4 h3 = Hl[(size_t)(q0.w & 0xffffu) << 4];
        uint4 h4 = Hl[(size_t)(q1.x & 0xffffu) << 4];
        uint4 h5 = Hl[(size_t)(q1.y & 0xffffu) << 4];
        uint4 h6 = Hl[(size_t)(q1.z & 0xffffu) << 4];
        uint4 h7 = Hl[(size_t)(q1.w & 0xffffu) << 4];
        unsigned int wb; __half2 w2;
#define ACC8(hh, wsrc)                                                        \
        wb = (wsrc) >> 16; w2 = u2h2(wb | (wb << 16));                        \
        a01 = __hfma2(u2h2(hh.x), w2, a01); a23 = __hfma2(u2h2(hh.y), w2, a23); \
        a45 = __hfma2(u2h2(hh.z), w2, a45); a67 = __hfma2(u2h2(hh.w), w2, a67);
        ACC8(h0, q0.x) ACC8(h1, q0.y) ACC8(h2, q0.z) ACC8(h3, q0.w)
        ACC8(h4, q1.x) ACC8(h5, q1.y) ACC8(h6, q1.z) ACC8(h7, q1.w)
#undef ACC8
    }
    float4 bv0 = ((const float4*)bias)[2 * l16];
    float4 bv1 = ((const float4*)bias)[2 * l16 + 1];
    float a0 = __low2float(a01) + bv0.x, a1 = __high2float(a01) + bv0.y;
    float a2 = __low2float(a23) + bv0.z, a3 = __high2float(a23) + bv0.w;
    float a4 = __low2float(a45) + bv1.x, a5 = __high2float(a45) + bv1.y;
    float a6 = __low2float(a67) + bv1.z, a7 = __high2float(a67) + bv1.w;
    float s = ((a0 + a1) + (a2 + a3)) + ((a4 + a5) + (a6 + a7));
#pragma unroll
    for (int m = 8; m >= 1; m >>= 1) s += __shfl_xor(s, m, 64);
    float mu = s * (1.f / 128.f);
    float d0 = a0 - mu, d1 = a1 - mu, d2 = a2 - mu, d3 = a3 - mu;
    float d4 = a4 - mu, d5 = a5 - mu, d6 = a6 - mu, d7 = a7 - mu;
    float q = ((d0 * d0 + d1 * d1) + (d2 * d2 + d3 * d3)) +
              ((d4 * d4 + d5 * d5) + (d6 * d6 + d7 * d7));
#pragma unroll
    for (int m = 8; m >= 1; m >>= 1) q += __shfl_xor(q, m, 64);
    float rs = rsqrtf(q * (1.f / 128.f) + LN_EPS);
    float4 gv0 = ((const float4*)g)[2 * l16], gv1 = ((const float4*)g)[2 * l16 + 1];
    float4 bev0 = ((const float4*)be)[2 * l16], bev1 = ((const float4*)be)[2 * l16 + 1];
    float r0 = fmaxf(d0 * rs * gv0.x + bev0.x, 0.f);
    float r1 = fmaxf(d1 * rs * gv0.y + bev0.y, 0.f);
    float r2 = fmaxf(d2 * rs * gv0.z + bev0.z, 0.f);
    float r3 = fmaxf(d3 * rs * gv0.w + bev0.w, 0.f);
    float r4 = fmaxf(d4 * rs * gv1.x + bev1.x, 0.f);
    float r5 = fmaxf(d5 * rs * gv1.y + bev1.y, 0.f);
    float r6 = fmaxf(d6 * rs * gv1.z + bev1.z, 0.f);
    float r7 = fmaxf(d7 * rs * gv1.w + bev1.w, 0.f);
    if (flags[0]) {
        float4* o = (float4*)outAny + (size_t)node * 32 + 2 * l16;
        o[0] = make_float4(r0, r1, r2, r3);
        o[1] = make_float4(r4, r5, r6, r7);
    } else {
        uint4 o;
        o.x = pk2(r0, r1); o.y = pk2(r2, r3);
        o.z = pk2(r4, r5); o.w = pk2(r6, r7);
        ((uint4*)outAny)[(size_t)node * 16 + l16] = o;
    }
}

extern "C" void kernel_launch(void* const* d_in, const int* in_sizes, int n_in,
                              void* d_out, int out_size, void* d_ws, size_t ws_size,
                              hipStream_t stream) {
    const unsigned short* x_u16 = (const unsigned short*)d_in[0];
    const int*            ei    = (const int*)d_in[1];

    const int N = in_sizes[0] / 128;
    const int E = in_sizes[2];
    const int B = (N + 255) >> 8;          // buckets of 256 nodes (<=256)
    const int chunk = (E + G1 - 1) / G1;

    // ---- workspace layout ----
    unsigned short* Hh2 = (unsigned short*)d_ws;           // N*128 f16 (layer2 gemm out)
    unsigned short* Hh  = Hh2 + (size_t)N * 128;           // N*128 f16 (layer1 gemm out)
    unsigned int* gA    = (unsigned int*)(Hh + (size_t)N * 128); // E
    unsigned int* edata = gA + E;                          // B*CAPB
    unsigned char* g8   = (unsigned char*)(edata + (size_t)B * CAPB); // E (pad 4)
    int* cnt2d  = (int*)(g8 + ((E + 3) & ~3));             // 256*256
    int* lofs2d = cnt2d + 65536;                           // 256*256
    uint2* nfo  = (uint2*)(lofs2d + 65536);                // N
    int* flags  = (int*)(nfo + N);                         // 8
    unsigned short* Wt1 = (unsigned short*)(flags + 8);    // 16384 bf16
    unsigned short* Wt2 = Wt1 + 16384;                     // 16384 bf16
    float* sm   = (float*)(Wt2 + 16384);                   // 6*128 f32
    float* b1f  = sm;
    float* b2f_ = sm + 128;
    float* g1f  = sm + 256;
    float* g2f  = sm + 384;
    float* be1f = sm + 512;
    float* be2f = sm + 640;

    const int nodeBlocks = (N + 15) / 16;
    const int gemmBlocks = (N + 63) / 64;

    // ---- pass1: edge binning + weight prep (merged, 320 blocks) ----
    k_p1<<<G1 + 64, 256, 0, stream>>>(x_u16, ei, d_in[2],
                                      d_in[3], d_in[5], d_in[4], d_in[6],
                                      d_in[7], d_in[9], d_in[8], d_in[10],
                                      Wt1, Wt2, sm,
                                      E, B, chunk, gA, g8, cnt2d, lofs2d, flags);

    // ---- pass3 CSR finalize + layer-1 GEMM (merged, independent roles) ----
    k_p3g<<<B + gemmBlocks, 256, 0, stream>>>(gA, g8, cnt2d, lofs2d, edata, nfo,
                                              d_in[0], Wt1, Hh, flags, N, B, chunk);

    // ---- layer-1 aggregate + LN + ReLU + layer-2 GEMM (fused) ----
    k_agg_gemm<<<nodeBlocks, 256, 0, stream>>>(Hh, edata, nfo, b1f, g1f, be1f,
                                               Wt2, Hh2, N);

    // ---- layer-2 aggregate + LN + ReLU -> d_out ----
    k_agg_ln<<<nodeBlocks, 256, 0, stream>>>(Hh2, edata, nfo, b2f_, g2f, be2f,
                                             d_out, flags, N);
}